// Round 2
// baseline (307.922 us; speedup 1.0000x reference)
//
#include <hip/hip_runtime.h>
#include <hip/hip_bf16.h>

typedef unsigned short u16;
typedef unsigned int u32;
typedef __attribute__((ext_vector_type(8))) short bf16x8;
typedef __attribute__((ext_vector_type(4))) float f32x4;

__device__ __forceinline__ u16 f2bf(float f) {
    u32 u = __float_as_uint(f);
    u32 r = (u + 0x7fffu + ((u >> 16) & 1u)) >> 16;   // RNE
    return (u16)r;
}
__device__ __forceinline__ float sx(float v, int m) { return __shfl_xor(v, m, 64); }

#define MROWS 32768
#define IN_D  512
#define OUT_D 512
#define KP    544
#define NQ    6

#define WS_XBF   0                       // u16 [32768][544]
#define WS_WBF   35651584                // u16 [512][544]
#define WS_WTRIG (35651584 + 557056)     // float[96]: 12 merged 2x2 complex mats

// ---------------------------------------------------------------------------
// kernel 0: pack W' = [skip_w | exit_w | 0] bf16; merged layer gates U=RZ*RY*RX
// ---------------------------------------------------------------------------
__global__ void k_setup(const float* __restrict__ skip_w,
                        const float* __restrict__ exit_w,
                        const float* __restrict__ vqc_w,
                        u16* __restrict__ Wbf,
                        float* __restrict__ wtrig) {
    int n = blockIdx.x;           // 512 blocks
    int t = threadIdx.x;          // 64 threads
    for (int c = t; c < KP; c += 64) {
        float v;
        if (c < 512)      v = skip_w[n * 512 + c];
        else if (c < 518) v = exit_w[n * 6 + (c - 512)];
        else              v = 0.0f;
        Wbf[n * KP + c] = f2bf(v);
    }
    if (blockIdx.x == 0 && t < 12) {
        int l = t / 6, i = t % 6;
        float c0 = cosf(0.5f * vqc_w[l * 18 + i]),      s0 = sinf(0.5f * vqc_w[l * 18 + i]);
        float c1 = cosf(0.5f * vqc_w[l * 18 + 6 + i]),  s1 = sinf(0.5f * vqc_w[l * 18 + 6 + i]);
        float c2 = cosf(0.5f * vqc_w[l * 18 + 12 + i]), s2 = sinf(0.5f * vqc_w[l * 18 + 12 + i]);
        // M = RY*RX
        float M00r = c1 * c0, M00i =  s1 * s0;
        float M01r = -s1 * c0, M01i = -c1 * s0;
        float M10r =  s1 * c0, M10i = -c1 * s0;
        float M11r = c1 * c0, M11i = -s1 * s0;
        // U = RZ*M : row0 *= (c2 - i s2), row1 *= (c2 + i s2)
        float* o = wtrig + t * 8;
        o[0] = M00r * c2 + M00i * s2;  o[1] = M00i * c2 - M00r * s2;
        o[2] = M01r * c2 + M01i * s2;  o[3] = M01i * c2 - M01r * s2;
        o[4] = M10r * c2 - M10i * s2;  o[5] = M10i * c2 + M10r * s2;
        o[6] = M11r * c2 - M11i * s2;  o[7] = M11i * c2 + M11r * s2;
    }
}

// ---------------------------------------------------------------------------
// register-statevector gate helpers (lane = one row; 64 amps in VGPRs)
// ---------------------------------------------------------------------------
template<int M>
__device__ __forceinline__ void g_real(float* sr, float* si,
                                       float g00, float g01, float g10, float g11) {
#pragma unroll
    for (int k = 0; k < 64; ++k) if (!(k & M)) {
        const int k1 = k | M;
        float a0 = sr[k], a1 = sr[k1];
        sr[k]  = g00 * a0 + g01 * a1;
        sr[k1] = g10 * a0 + g11 * a1;
        float b0 = si[k], b1 = si[k1];
        si[k]  = g00 * b0 + g01 * b1;
        si[k1] = g10 * b0 + g11 * b1;
    }
}
template<int M>
__device__ __forceinline__ void g_ry(float* sr, float* si, float c, float s) {
    g_real<M>(sr, si, c, -s, s, c);
}
template<int M>
__device__ __forceinline__ void g_rz(float* sr, float* si, float c, float s) {
#pragma unroll
    for (int k = 0; k < 64; ++k) {
        float u = (k & M) ? -s : s;
        float ar = sr[k], ai = si[k];
        sr[k] = c * ar + u * ai;
        si[k] = c * ai - u * ar;
    }
}
template<int CM, int TM>
__device__ __forceinline__ void g_cnot(float* sr, float* si) {
#pragma unroll
    for (int k = 0; k < 64; ++k) if ((k & CM) && !(k & TM)) {
        const int k1 = k | TM;
        float t = sr[k]; sr[k] = sr[k1]; sr[k1] = t;
        t = si[k]; si[k] = si[k1]; si[k1] = t;
    }
}
template<int M>
__device__ __forceinline__ void g_u(float* sr, float* si,
                                    float2 u00, float2 u01, float2 u10, float2 u11) {
#pragma unroll
    for (int k = 0; k < 64; ++k) if (!(k & M)) {
        const int k1 = k | M;
        float a0r = sr[k], a0i = si[k], a1r = sr[k1], a1i = si[k1];
        sr[k]  = u00.x * a0r - u00.y * a0i + u01.x * a1r - u01.y * a1i;
        si[k]  = u00.x * a0i + u00.y * a0r + u01.x * a1i + u01.y * a1r;
        sr[k1] = u10.x * a0r - u10.y * a0i + u11.x * a1r - u11.y * a1i;
        si[k1] = u10.x * a0i + u10.y * a0r + u11.x * a1i + u11.y * a1r;
    }
}

// ---------------------------------------------------------------------------
// kernel 1: z = entry GEMV (wave-per-row) + register statevector sim (lane=row)
// ---------------------------------------------------------------------------
__global__ __launch_bounds__(64) void k_zq(const float* __restrict__ x,
                                           const float* __restrict__ entry_w,
                                           const float* __restrict__ entry_b,
                                           const float* __restrict__ wtrig,
                                           u16* __restrict__ xbf) {
    const int lane = threadIdx.x;
    const int r0 = blockIdx.x * 64;

    float4 wA[NQ], wB[NQ];
#pragma unroll
    for (int j = 0; j < NQ; ++j) {
        const float4* wp = (const float4*)(entry_w + j * IN_D) + lane * 2;
        wA[j] = wp[0]; wB[j] = wp[1];
    }
    float eb[NQ];
#pragma unroll
    for (int j = 0; j < NQ; ++j) eb[j] = entry_b[j];

    float zk[NQ];
#pragma unroll
    for (int j = 0; j < NQ; ++j) zk[j] = 0.0f;

#pragma unroll 1
    for (int r = 0; r < 64; ++r) {
        const int row = r0 + r;
        const float4* xp = (const float4*)(x + (size_t)row * IN_D) + lane * 2;
        float4 xa = xp[0], xb = xp[1];
        union { u16 u[8]; uint4 v; } pk;
        pk.u[0] = f2bf(xa.x); pk.u[1] = f2bf(xa.y); pk.u[2] = f2bf(xa.z); pk.u[3] = f2bf(xa.w);
        pk.u[4] = f2bf(xb.x); pk.u[5] = f2bf(xb.y); pk.u[6] = f2bf(xb.z); pk.u[7] = f2bf(xb.w);
        *(uint4*)(xbf + (size_t)row * KP + lane * 8) = pk.v;
        float d[NQ];
#pragma unroll
        for (int j = 0; j < NQ; ++j)
            d[j] = xa.x * wA[j].x + xa.y * wA[j].y + xa.z * wA[j].z + xa.w * wA[j].w
                 + xb.x * wB[j].x + xb.y * wB[j].y + xb.z * wB[j].z + xb.w * wB[j].w;
#pragma unroll
        for (int off = 1; off < 64; off <<= 1)
#pragma unroll
            for (int j = 0; j < NQ; ++j) d[j] += sx(d[j], off);
#pragma unroll
        for (int j = 0; j < NQ; ++j) zk[j] = (lane == r) ? d[j] + eb[j] : zk[j];
    }

    // closed-form half-angle trig for RY(atan z), RZ(atan z^2), this lane's row
    float cy[NQ], sy[NQ], cz[NQ], szv[NQ];
#pragma unroll
    for (int j = 0; j < NQ; ++j) {
        float zj = zk[j];
        float c1 = rsqrtf(1.0f + zj * zj);
        cy[j] = sqrtf(0.5f * (1.0f + c1));
        sy[j] = copysignf(sqrtf(fmaxf(0.5f * (1.0f - c1), 0.0f)), zj);
        float w  = zj * zj;
        float c2 = rsqrtf(1.0f + w * w);
        cz[j] = sqrtf(0.5f * (1.0f + c2));
        szv[j] = sqrtf(fmaxf(0.5f * (1.0f - c2), 0.0f));
    }

    float sr[64], si[64];
#pragma unroll
    for (int k = 0; k < 64; ++k) { sr[k] = 0.0f; si[k] = 0.0f; }
    sr[0] = 1.0f;

    const float Kc = 0.70710678118f;
    // encoding: (RY*H) merged real gate, then RZ
#define ENC(i) { float g00 = Kc * (cy[i] - sy[i]), g01 = Kc * (cy[i] + sy[i]); \
                 float g10 = Kc * (sy[i] + cy[i]), g11 = Kc * (sy[i] - cy[i]); \
                 g_real<(1 << i)>(sr, si, g00, g01, g10, g11); \
                 g_rz<(1 << i)>(sr, si, cz[i], szv[i]); }
    ENC(0) ENC(1) ENC(2) ENC(3) ENC(4) ENC(5)
#undef ENC

    const float2* wu = (const float2*)wtrig;
#pragma unroll
    for (int l = 0; l < 2; ++l) {
        g_cnot<1, 2>(sr, si);  g_cnot<2, 4>(sr, si);   g_cnot<4, 8>(sr, si);
        g_cnot<8, 16>(sr, si); g_cnot<16, 32>(sr, si); g_cnot<32, 1>(sr, si);
#define ROT(i) { int b = (l * 6 + i) * 4; g_u<(1 << i)>(sr, si, wu[b], wu[b + 1], wu[b + 2], wu[b + 3]); }
        ROT(0) ROT(1) ROT(2) ROT(3) ROT(4) ROT(5)
#undef ROT
        if (l == 0) {
#define REUP(i) { g_ry<(1 << i)>(sr, si, cy[i], sy[i]); g_rz<(1 << i)>(sr, si, cz[i], szv[i]); }
            REUP(0) REUP(1) REUP(2) REUP(3) REUP(4) REUP(5)
#undef REUP
        }
    }

    // measure <Z_i> = 2*sum_{bit_i=0} p - total
    float tot = 0.0f, sb[NQ];
#pragma unroll
    for (int i = 0; i < NQ; ++i) sb[i] = 0.0f;
#pragma unroll
    for (int k = 0; k < 64; ++k) {
        float p = sr[k] * sr[k] + si[k] * si[k];
        tot += p;
#pragma unroll
        for (int i = 0; i < NQ; ++i) if (!(k & (1 << i))) sb[i] += p;
    }

    union { u16 u[8]; uint4 v; } t0;
#pragma unroll
    for (int j = 0; j < NQ; ++j) t0.u[j] = f2bf(zk[j] + (2.0f * sb[j] - tot));
    t0.u[6] = 0; t0.u[7] = 0;
    uint4 zz; zz.x = zz.y = zz.z = zz.w = 0;
    u16* dst = xbf + (size_t)(r0 + lane) * KP + 512;
    *(uint4*)(dst)      = t0.v;
    *(uint4*)(dst + 8)  = zz;
    *(uint4*)(dst + 16) = zz;
    *(uint4*)(dst + 24) = zz;
}

// ---------------------------------------------------------------------------
// kernel 2: C = A'[32768][544] @ W'[512][544]^T via global_load_lds staging,
// + bias, LN over full 512-row, store fp32. 64x512 tile, 8 waves.
// ---------------------------------------------------------------------------
__global__ __launch_bounds__(512) void k_gemm_ln(const u16* __restrict__ xbf,
                                                 const u16* __restrict__ Wbf,
                                                 const float* __restrict__ skip_b,
                                                 const float* __restrict__ exit_b,
                                                 const float* __restrict__ gamma,
                                                 const float* __restrict__ beta,
                                                 float* __restrict__ out) {
    // 36 groups x 1024 B: groups 0..3 = A (64x32), 4..35 = B (512x32)
    __shared__ __align__(16) u16 sAB[36 * 512];
    __shared__ float ps[8][64][2];
    __shared__ float stats[64][2];

    const int tid  = threadIdx.x;
    const int wid  = tid >> 6;
    const int lane = tid & 63;
    const int q    = lane >> 4;
    const int c16  = lane & 15;
    const int m0   = blockIdx.x * 64;
    const int mc   = (c16 ^ (c16 >> 2)) & 3;   // read-side swizzle

    f32x4 acc[4][4];
#pragma unroll
    for (int mt = 0; mt < 4; ++mt)
#pragma unroll
        for (int nt = 0; nt < 4; ++nt)
#pragma unroll
            for (int r = 0; r < 4; ++r) acc[mt][nt][r] = 0.0f;

    // staging-side per-lane chunk permutation
    const int rowLocal = lane >> 2;
    const int j4 = (lane & 3) ^ ((rowLocal ^ (rowLocal >> 2)) & 3);

    for (int ks = 0; ks < 17; ++ks) {
#pragma unroll
        for (int r = 0; r < 5; ++r) {
            const int g = r * 8 + wid;           // group id, wave-uniform
            if (g < 36) {
                const u16* src;
                if (g < 4) {
                    int i = g * 16 + rowLocal;
                    src = xbf + (size_t)(m0 + i) * KP + ks * 32 + j4 * 8;
                } else {
                    int n = (g - 4) * 16 + rowLocal;
                    src = Wbf + (size_t)n * KP + ks * 32 + j4 * 8;
                }
                __builtin_amdgcn_global_load_lds(
                    (const __attribute__((address_space(1))) u32*)src,
                    (__attribute__((address_space(3))) u32*)(sAB + g * 512),
                    16, 0, 0);
            }
        }
        __syncthreads();

        bf16x8 af[4], bfr[4];
#pragma unroll
        for (int mt = 0; mt < 4; ++mt)
            af[mt] = *(const bf16x8*)(sAB + mt * 512 + (c16 * 4 + (q ^ mc)) * 8);
#pragma unroll
        for (int nt = 0; nt < 4; ++nt)
            bfr[nt] = *(const bf16x8*)(sAB + (4 + wid * 4 + nt) * 512 + (c16 * 4 + (q ^ mc)) * 8);
#pragma unroll
        for (int mt = 0; mt < 4; ++mt)
#pragma unroll
            for (int nt = 0; nt < 4; ++nt)
                acc[mt][nt] = __builtin_amdgcn_mfma_f32_16x16x32_bf16(af[mt], bfr[nt], acc[mt][nt], 0, 0, 0);
        __syncthreads();
    }

    // epilogue: bias, LN over 512 cols (full row in block), store fp32
    float bias[4], gg[4], bb[4];
#pragma unroll
    for (int nt = 0; nt < 4; ++nt) {
        int n = wid * 64 + nt * 16 + c16;
        bias[nt] = skip_b[n] + exit_b[n];
        gg[nt] = gamma[n];
        bb[nt] = beta[n];
    }
#pragma unroll
    for (int mt = 0; mt < 4; ++mt)
#pragma unroll
        for (int nt = 0; nt < 4; ++nt)
#pragma unroll
            for (int r = 0; r < 4; ++r) acc[mt][nt][r] += bias[nt];

#pragma unroll
    for (int mt = 0; mt < 4; ++mt)
#pragma unroll
        for (int r = 0; r < 4; ++r) {
            float s1 = 0.0f, s2 = 0.0f;
#pragma unroll
            for (int nt = 0; nt < 4; ++nt) {
                float v = acc[mt][nt][r];
                s1 += v; s2 += v * v;
            }
#pragma unroll
            for (int off = 1; off < 16; off <<= 1) {
                s1 += sx(s1, off);
                s2 += sx(s2, off);
            }
            if (c16 == r) {
                int m = mt * 16 + q * 4 + r;
                ps[wid][m][0] = s1;
                ps[wid][m][1] = s2;
            }
        }
    __syncthreads();
    if (tid < 64) {
        float s1 = 0.0f, s2 = 0.0f;
#pragma unroll
        for (int w2 = 0; w2 < 8; ++w2) { s1 += ps[w2][tid][0]; s2 += ps[w2][tid][1]; }
        float mu  = s1 * (1.0f / 512.0f);
        float var = s2 * (1.0f / 512.0f) - mu * mu;
        stats[tid][0] = mu;
        stats[tid][1] = rsqrtf(var + 1e-5f);
    }
    __syncthreads();

#pragma unroll
    for (int mt = 0; mt < 4; ++mt)
#pragma unroll
        for (int r = 0; r < 4; ++r) {
            int m = mt * 16 + q * 4 + r;
            float mu = stats[m][0], rs = stats[m][1];
#pragma unroll
            for (int nt = 0; nt < 4; ++nt) {
                float v = (acc[mt][nt][r] - mu) * rs * gg[nt] + bb[nt];
                out[(size_t)(m0 + m) * OUT_D + wid * 64 + nt * 16 + c16] = v;
            }
        }
}

// ---------------------------------------------------------------------------
extern "C" void kernel_launch(void* const* d_in, const int* in_sizes, int n_in,
                              void* d_out, int out_size, void* d_ws, size_t ws_size,
                              hipStream_t stream) {
    const float* x       = (const float*)d_in[0];
    const float* entry_w = (const float*)d_in[1];
    const float* entry_b = (const float*)d_in[2];
    const float* exit_w  = (const float*)d_in[3];
    const float* exit_b  = (const float*)d_in[4];
    const float* skip_w  = (const float*)d_in[5];
    const float* skip_b  = (const float*)d_in[6];
    const float* vqc_w   = (const float*)d_in[7];
    const float* gamma   = (const float*)d_in[8];
    const float* beta    = (const float*)d_in[9];
    float* out = (float*)d_out;

    char* ws = (char*)d_ws;
    u16*   xbf   = (u16*)(ws + WS_XBF);
    u16*   Wbf   = (u16*)(ws + WS_WBF);
    float* wtrig = (float*)(ws + WS_WTRIG);

    k_setup<<<dim3(512), dim3(64), 0, stream>>>(skip_w, exit_w, vqc_w, Wbf, wtrig);
    k_zq<<<dim3(MROWS / 64), dim3(64), 0, stream>>>(x, entry_w, entry_b, wtrig, xbf);
    k_gemm_ln<<<dim3(MROWS / 64), dim3(512), 0, stream>>>(xbf, Wbf, skip_b, exit_b, gamma, beta, out);
}

// Round 3
// 235.714 us; speedup vs baseline: 1.3063x; 1.3063x over previous
//
#include <hip/hip_runtime.h>
#include <hip/hip_bf16.h>

typedef unsigned short u16;
typedef unsigned int u32;
typedef __attribute__((ext_vector_type(8))) short bf16x8;
typedef __attribute__((ext_vector_type(4))) float f32x4;

__device__ __forceinline__ u16 f2bf(float f) {
    u32 u = __float_as_uint(f);
    u32 r = (u + 0x7fffu + ((u >> 16) & 1u)) >> 16;   // RNE
    return (u16)r;
}
__device__ __forceinline__ float sx(float v, int m) { return __shfl_xor(v, m, 64); }

#define MROWS 32768
#define IN_D  512
#define OUT_D 512
#define KP    544
#define NQ    6

#define WS_XBF   0                       // u16 [32768][544]
#define WS_WBF   35651584                // u16 [512][544]
#define WS_WTRIG (35651584 + 557056)     // float[96]: 12 merged 2x2 complex mats

// ---------------------------------------------------------------------------
// kernel 0: pack W' = [skip_w | exit_w | 0] bf16; merged layer gates U=RZ*RY*RX
// ---------------------------------------------------------------------------
__global__ void k_setup(const float* __restrict__ skip_w,
                        const float* __restrict__ exit_w,
                        const float* __restrict__ vqc_w,
                        u16* __restrict__ Wbf,
                        float* __restrict__ wtrig) {
    int n = blockIdx.x;           // 512 blocks
    int t = threadIdx.x;          // 64 threads
    for (int c = t; c < KP; c += 64) {
        float v;
        if (c < 512)      v = skip_w[n * 512 + c];
        else if (c < 518) v = exit_w[n * 6 + (c - 512)];
        else              v = 0.0f;
        Wbf[n * KP + c] = f2bf(v);
    }
    if (blockIdx.x == 0 && t < 12) {
        int l = t / 6, i = t % 6;
        float c0 = cosf(0.5f * vqc_w[l * 18 + i]),      s0 = sinf(0.5f * vqc_w[l * 18 + i]);
        float c1 = cosf(0.5f * vqc_w[l * 18 + 6 + i]),  s1 = sinf(0.5f * vqc_w[l * 18 + 6 + i]);
        float c2 = cosf(0.5f * vqc_w[l * 18 + 12 + i]), s2 = sinf(0.5f * vqc_w[l * 18 + 12 + i]);
        // M = RY*RX
        float M00r = c1 * c0, M00i =  s1 * s0;
        float M01r = -s1 * c0, M01i = -c1 * s0;
        float M10r =  s1 * c0, M10i = -c1 * s0;
        float M11r = c1 * c0, M11i = -s1 * s0;
        // U = RZ*M : row0 *= (c2 - i s2), row1 *= (c2 + i s2)
        float* o = wtrig + t * 8;
        o[0] = M00r * c2 + M00i * s2;  o[1] = M00i * c2 - M00r * s2;
        o[2] = M01r * c2 + M01i * s2;  o[3] = M01i * c2 - M01r * s2;
        o[4] = M10r * c2 - M10i * s2;  o[5] = M10i * c2 + M10r * s2;
        o[6] = M11r * c2 - M11i * s2;  o[7] = M11i * c2 + M11r * s2;
    }
}

// ---------------------------------------------------------------------------
// 16-amp register-slice gate helpers: 4 lanes per row, lane sub=(lane&3)
// holds amps k = sub*16 + m (m=0..15). Qubits 0-3 in-register; 4,5 cross-lane.
// ---------------------------------------------------------------------------
template<int M>
__device__ __forceinline__ void r16_real(float* ar, float* ai,
                                         float g00, float g01, float g10, float g11) {
#pragma unroll
    for (int k = 0; k < 16; ++k) if (!(k & M)) {
        const int k1 = k | M;
        float a0 = ar[k], a1 = ar[k1];
        ar[k]  = g00 * a0 + g01 * a1;
        ar[k1] = g10 * a0 + g11 * a1;
        float b0 = ai[k], b1 = ai[k1];
        ai[k]  = g00 * b0 + g01 * b1;
        ai[k1] = g10 * b0 + g11 * b1;
    }
}
template<int M>
__device__ __forceinline__ void r16_rz(float* ar, float* ai, float c, float s) {
#pragma unroll
    for (int k = 0; k < 16; ++k) {
        float u = (k & M) ? -s : s;
        float nr = c * ar[k] + u * ai[k];
        ai[k] = c * ai[k] - u * ar[k];
        ar[k] = nr;
    }
}
template<int M>
__device__ __forceinline__ void r16_cplx(float* ar, float* ai,
                                         float2 u00, float2 u01, float2 u10, float2 u11) {
#pragma unroll
    for (int k = 0; k < 16; ++k) if (!(k & M)) {
        const int k1 = k | M;
        float a0r = ar[k], a0i = ai[k], a1r = ar[k1], a1i = ai[k1];
        ar[k]  = u00.x * a0r - u00.y * a0i + u01.x * a1r - u01.y * a1i;
        ai[k]  = u00.x * a0i + u00.y * a0r + u01.x * a1i + u01.y * a1r;
        ar[k1] = u10.x * a0r - u10.y * a0i + u11.x * a1r - u11.y * a1i;
        ai[k1] = u10.x * a0i + u10.y * a0r + u11.x * a1i + u11.y * a1r;
    }
}
template<int CM, int TM>
__device__ __forceinline__ void r16_cnot(float* ar, float* ai) {
#pragma unroll
    for (int k = 0; k < 16; ++k) if ((k & CM) && !(k & TM)) {
        const int k1 = k | TM;
        float t = ar[k]; ar[k] = ar[k1]; ar[k1] = t;
        t = ai[k]; ai[k] = ai[k1]; ai[k1] = t;
    }
}
__device__ __forceinline__ void x16_real(float* ar, float* ai, int xm, bool b,
                                         float g00, float g01, float g10, float g11) {
    float gs = b ? g11 : g00, go = b ? g10 : g01;
#pragma unroll
    for (int k = 0; k < 16; ++k) {
        float pr = sx(ar[k], xm), pi = sx(ai[k], xm);
        ar[k] = gs * ar[k] + go * pr;
        ai[k] = gs * ai[k] + go * pi;
    }
}
__device__ __forceinline__ void x16_rz(float* ar, float* ai, bool b, float c, float s) {
    float u = b ? -s : s;
#pragma unroll
    for (int k = 0; k < 16; ++k) {
        float nr = c * ar[k] + u * ai[k];
        ai[k] = c * ai[k] - u * ar[k];
        ar[k] = nr;
    }
}
__device__ __forceinline__ void x16_cplx(float* ar, float* ai, int xm, bool b,
                                         float2 u00, float2 u01, float2 u10, float2 u11) {
    float2 us, uo;
    us.x = b ? u11.x : u00.x; us.y = b ? u11.y : u00.y;
    uo.x = b ? u10.x : u01.x; uo.y = b ? u10.y : u01.y;
#pragma unroll
    for (int k = 0; k < 16; ++k) {
        float pr = sx(ar[k], xm), pi = sx(ai[k], xm);
        float nr = us.x * ar[k] - us.y * ai[k] + uo.x * pr - uo.y * pi;
        ai[k] = us.x * ai[k] + us.y * ar[k] + uo.x * pi + uo.y * pr;
        ar[k] = nr;
    }
}

// ---------------------------------------------------------------------------
// kernel 1: entry GEMV + statevector sim, 4 lanes per row (2048 waves total)
// ---------------------------------------------------------------------------
__global__ __launch_bounds__(256) void k_zq(const float* __restrict__ x,
                                            const float* __restrict__ entry_w,
                                            const float* __restrict__ entry_b,
                                            const float* __restrict__ wtrig,
                                            u16* __restrict__ xbf) {
    const int lane = threadIdx.x & 63;
    const int wid  = threadIdx.x >> 6;
    const int grp  = lane >> 2;
    const int sub  = lane & 3;
    const int row  = blockIdx.x * 64 + wid * 16 + grp;
    const bool b4 = (sub & 1) != 0;
    const bool b5 = (sub & 2) != 0;

    // ---- phase 1: lane covers cols [i*32+sub*8, +8) : dot + bf16 pack ----
    float d[NQ] = {0, 0, 0, 0, 0, 0};
#pragma unroll 4
    for (int i = 0; i < 16; ++i) {
        const float4* xp = (const float4*)(x + (size_t)row * IN_D + i * 32 + sub * 8);
        float4 xa = xp[0], xb = xp[1];
        union { u16 u[8]; uint4 v; } pk;
        pk.u[0] = f2bf(xa.x); pk.u[1] = f2bf(xa.y); pk.u[2] = f2bf(xa.z); pk.u[3] = f2bf(xa.w);
        pk.u[4] = f2bf(xb.x); pk.u[5] = f2bf(xb.y); pk.u[6] = f2bf(xb.z); pk.u[7] = f2bf(xb.w);
        *(uint4*)(xbf + (size_t)row * KP + i * 32 + sub * 8) = pk.v;
#pragma unroll
        for (int j = 0; j < NQ; ++j) {
            const float4* wp = (const float4*)(entry_w + j * IN_D + i * 32 + sub * 8);
            float4 wa = wp[0], wb = wp[1];
            d[j] += xa.x * wa.x + xa.y * wa.y + xa.z * wa.z + xa.w * wa.w
                  + xb.x * wb.x + xb.y * wb.y + xb.z * wb.z + xb.w * wb.w;
        }
    }
    float z[NQ];
#pragma unroll
    for (int j = 0; j < NQ; ++j) {
        d[j] += sx(d[j], 1);
        d[j] += sx(d[j], 2);
        z[j] = d[j] + entry_b[j];
    }

    // ---- trig (replicated across the 4 lanes of the row) ----
    float cy[NQ], sy[NQ], cz[NQ], szv[NQ];
#pragma unroll
    for (int j = 0; j < NQ; ++j) {
        float zj = z[j];
        float c1 = rsqrtf(1.0f + zj * zj);
        cy[j] = sqrtf(0.5f * (1.0f + c1));
        sy[j] = copysignf(sqrtf(fmaxf(0.5f * (1.0f - c1), 0.0f)), zj);
        float w  = zj * zj;
        float c2 = rsqrtf(1.0f + w * w);
        cz[j] = sqrtf(0.5f * (1.0f + c2));
        szv[j] = sqrtf(fmaxf(0.5f * (1.0f - c2), 0.0f));
    }

    // ---- phase 2: statevector, 16 amps/lane ----
    float ar[16], ai[16];
#pragma unroll
    for (int k = 0; k < 16; ++k) { ar[k] = 0.0f; ai[k] = 0.0f; }
    if (sub == 0) ar[0] = 1.0f;

    const float Kc = 0.70710678118f;
    // encoding: (RY*H) real gate then RZ, per qubit
#define ENCR(i) { float g00 = Kc*(cy[i]-sy[i]), g01 = Kc*(cy[i]+sy[i]); \
                  float g10 = Kc*(sy[i]+cy[i]), g11 = Kc*(sy[i]-cy[i]); \
                  r16_real<(1 << i)>(ar, ai, g00, g01, g10, g11); \
                  r16_rz<(1 << i)>(ar, ai, cz[i], szv[i]); }
    ENCR(0) ENCR(1) ENCR(2) ENCR(3)
#undef ENCR
    { float g00 = Kc*(cy[4]-sy[4]), g01 = Kc*(cy[4]+sy[4]);
      float g10 = Kc*(sy[4]+cy[4]), g11 = Kc*(sy[4]-cy[4]);
      x16_real(ar, ai, 1, b4, g00, g01, g10, g11);
      x16_rz(ar, ai, b4, cz[4], szv[4]); }
    { float g00 = Kc*(cy[5]-sy[5]), g01 = Kc*(cy[5]+sy[5]);
      float g10 = Kc*(sy[5]+cy[5]), g11 = Kc*(sy[5]-cy[5]);
      x16_real(ar, ai, 2, b5, g00, g01, g10, g11);
      x16_rz(ar, ai, b5, cz[5], szv[5]); }

    const float2* wu = (const float2*)wtrig;
#pragma unroll
    for (int l = 0; l < 2; ++l) {
        // CNOT ring (0,1)(1,2)(2,3) in-register
        r16_cnot<1, 2>(ar, ai); r16_cnot<2, 4>(ar, ai); r16_cnot<4, 8>(ar, ai);
        // (3,4): ctrl bit3 in-reg, tgt bit4 cross (xor 1)
#pragma unroll
        for (int k = 0; k < 16; ++k) if (k & 8) {
            ar[k] = sx(ar[k], 1); ai[k] = sx(ai[k], 1);
        }
        // (4,5): ctrl bit4 = sub&1, tgt bit5 cross (xor 2)
#pragma unroll
        for (int k = 0; k < 16; ++k) {
            float pr = sx(ar[k], 2); ar[k] = b4 ? pr : ar[k];
            float pi = sx(ai[k], 2); ai[k] = b4 ? pi : ai[k];
        }
        // (5,0): ctrl bit5 = sub&2, tgt bit0 in-reg
#pragma unroll
        for (int k = 0; k < 16; k += 2) {
            float t0r = ar[k], t0i = ai[k];
            ar[k]     = b5 ? ar[k + 1] : ar[k];
            ai[k]     = b5 ? ai[k + 1] : ai[k];
            ar[k + 1] = b5 ? t0r : ar[k + 1];
            ai[k + 1] = b5 ? t0i : ai[k + 1];
        }
        // merged parameterized rotations U = RZ*RY*RX
#define ROTR(i) { int bx = (l * 6 + i) * 4; \
                  r16_cplx<(1 << i)>(ar, ai, wu[bx], wu[bx+1], wu[bx+2], wu[bx+3]); }
        ROTR(0) ROTR(1) ROTR(2) ROTR(3)
#undef ROTR
        { int bx = (l * 6 + 4) * 4; x16_cplx(ar, ai, 1, b4, wu[bx], wu[bx+1], wu[bx+2], wu[bx+3]); }
        { int bx = (l * 6 + 5) * 4; x16_cplx(ar, ai, 2, b5, wu[bx], wu[bx+1], wu[bx+2], wu[bx+3]); }
        // data re-upload after layer 0
        if (l == 0) {
#define REUPR(i) { r16_real<(1 << i)>(ar, ai, cy[i], -sy[i], sy[i], cy[i]); \
                   r16_rz<(1 << i)>(ar, ai, cz[i], szv[i]); }
            REUPR(0) REUPR(1) REUPR(2) REUPR(3)
#undef REUPR
            x16_real(ar, ai, 1, b4, cy[4], -sy[4], sy[4], cy[4]);
            x16_rz(ar, ai, b4, cz[4], szv[4]);
            x16_real(ar, ai, 2, b5, cy[5], -sy[5], sy[5], cy[5]);
            x16_rz(ar, ai, b5, cz[5], szv[5]);
        }
    }

    // ---- measure <Z_i> ----
    float e[NQ] = {0, 0, 0, 0, 0, 0};
    float tl = 0.0f;
#pragma unroll
    for (int k = 0; k < 16; ++k) {
        float p = ar[k] * ar[k] + ai[k] * ai[k];
        tl += p;
        e[0] += (k & 1) ? -p : p;
        e[1] += (k & 2) ? -p : p;
        e[2] += (k & 4) ? -p : p;
        e[3] += (k & 8) ? -p : p;
    }
    e[4] = b4 ? -tl : tl;
    e[5] = b5 ? -tl : tl;
#pragma unroll
    for (int j = 0; j < NQ; ++j) {
        e[j] += sx(e[j], 1);
        e[j] += sx(e[j], 2);
    }

    // ---- write tail [512..543]: 4 lanes x 16B ----
    union { u16 u[8]; uint4 v; } t0;
#pragma unroll
    for (int j = 0; j < NQ; ++j) t0.u[j] = f2bf(z[j] + e[j]);
    t0.u[6] = 0; t0.u[7] = 0;
    uint4 tv; tv.x = tv.y = tv.z = tv.w = 0;
    if (sub == 0) tv = t0.v;
    *(uint4*)(xbf + (size_t)row * KP + 512 + sub * 8) = tv;
}

// ---------------------------------------------------------------------------
// kernel 2: C = A'[32768][544] @ W'[512][544]^T, fragments loaded DIRECTLY
// from global (L2-served, native MFMA layout) — no LDS, no K-loop barriers.
// 64x512 tile, 8 waves; fused bias + LN + fp32 store.
// ---------------------------------------------------------------------------
__global__ __launch_bounds__(512) void k_gemm_ln(const u16* __restrict__ xbf,
                                                 const u16* __restrict__ Wbf,
                                                 const float* __restrict__ skip_b,
                                                 const float* __restrict__ exit_b,
                                                 const float* __restrict__ gamma,
                                                 const float* __restrict__ beta,
                                                 float* __restrict__ out) {
    __shared__ float ps[8][64][2];
    __shared__ float stats[64][2];

    const int tid  = threadIdx.x;
    const int wid  = tid >> 6;
    const int lane = tid & 63;
    const int q    = lane >> 4;
    const int c16  = lane & 15;
    const int m0   = blockIdx.x * 64;

    f32x4 acc[4][4];
#pragma unroll
    for (int mt = 0; mt < 4; ++mt)
#pragma unroll
        for (int nt = 0; nt < 4; ++nt)
#pragma unroll
            for (int r = 0; r < 4; ++r) acc[mt][nt][r] = 0.0f;

    // fragment base pointers: lane c16 -> row, q -> 16B k-chunk (native layout)
    const u16* aB = xbf + (size_t)(m0 + c16) * KP + q * 8;
    const u16* bB = Wbf + (size_t)(wid * 64 + c16) * KP + q * 8;

#pragma unroll 2
    for (int ks = 0; ks < 17; ++ks) {
        bf16x8 af[4], bfr[4];
#pragma unroll
        for (int mt = 0; mt < 4; ++mt)
            af[mt] = *(const bf16x8*)(aB + (size_t)mt * 16 * KP + ks * 32);
#pragma unroll
        for (int nt = 0; nt < 4; ++nt)
            bfr[nt] = *(const bf16x8*)(bB + (size_t)nt * 16 * KP + ks * 32);
#pragma unroll
        for (int mt = 0; mt < 4; ++mt)
#pragma unroll
            for (int nt = 0; nt < 4; ++nt)
                acc[mt][nt] = __builtin_amdgcn_mfma_f32_16x16x32_bf16(af[mt], bfr[nt], acc[mt][nt], 0, 0, 0);
    }

    // ---- epilogue: bias, LN over full 512-col row, store fp32 ----
    float bias[4], gg[4], bb[4];
#pragma unroll
    for (int nt = 0; nt < 4; ++nt) {
        int n = wid * 64 + nt * 16 + c16;
        bias[nt] = skip_b[n] + exit_b[n];
        gg[nt] = gamma[n];
        bb[nt] = beta[n];
    }
#pragma unroll
    for (int mt = 0; mt < 4; ++mt)
#pragma unroll
        for (int nt = 0; nt < 4; ++nt)
#pragma unroll
            for (int r = 0; r < 4; ++r) acc[mt][nt][r] += bias[nt];

#pragma unroll
    for (int mt = 0; mt < 4; ++mt)
#pragma unroll
        for (int r = 0; r < 4; ++r) {
            float s1 = 0.0f, s2 = 0.0f;
#pragma unroll
            for (int nt = 0; nt < 4; ++nt) {
                float v = acc[mt][nt][r];
                s1 += v; s2 += v * v;
            }
#pragma unroll
            for (int off = 1; off < 16; off <<= 1) {
                s1 += sx(s1, off);
                s2 += sx(s2, off);
            }
            if (c16 == r) {
                int m = mt * 16 + q * 4 + r;
                ps[wid][m][0] = s1;
                ps[wid][m][1] = s2;
            }
        }
    __syncthreads();
    if (tid < 64) {
        float s1 = 0.0f, s2 = 0.0f;
#pragma unroll
        for (int w2 = 0; w2 < 8; ++w2) { s1 += ps[w2][tid][0]; s2 += ps[w2][tid][1]; }
        float mu  = s1 * (1.0f / 512.0f);
        float var = s2 * (1.0f / 512.0f) - mu * mu;
        stats[tid][0] = mu;
        stats[tid][1] = rsqrtf(var + 1e-5f);
    }
    __syncthreads();

#pragma unroll
    for (int mt = 0; mt < 4; ++mt)
#pragma unroll
        for (int r = 0; r < 4; ++r) {
            int m = mt * 16 + q * 4 + r;
            float mu = stats[m][0], rs = stats[m][1];
#pragma unroll
            for (int nt = 0; nt < 4; ++nt) {
                float v = (acc[mt][nt][r] - mu) * rs * gg[nt] + bb[nt];
                out[(size_t)(m0 + m) * OUT_D + wid * 64 + nt * 16 + c16] = v;
            }
        }
}

// ---------------------------------------------------------------------------
extern "C" void kernel_launch(void* const* d_in, const int* in_sizes, int n_in,
                              void* d_out, int out_size, void* d_ws, size_t ws_size,
                              hipStream_t stream) {
    const float* x       = (const float*)d_in[0];
    const float* entry_w = (const float*)d_in[1];
    const float* entry_b = (const float*)d_in[2];
    const float* exit_w  = (const float*)d_in[3];
    const float* exit_b  = (const float*)d_in[4];
    const float* skip_w  = (const float*)d_in[5];
    const float* skip_b  = (const float*)d_in[6];
    const float* vqc_w   = (const float*)d_in[7];
    const float* gamma   = (const float*)d_in[8];
    const float* beta    = (const float*)d_in[9];
    float* out = (float*)d_out;

    char* ws = (char*)d_ws;
    u16*   xbf   = (u16*)(ws + WS_XBF);
    u16*   Wbf   = (u16*)(ws + WS_WBF);
    float* wtrig = (float*)(ws + WS_WTRIG);

    k_setup<<<dim3(512), dim3(64), 0, stream>>>(skip_w, exit_w, vqc_w, Wbf, wtrig);
    k_zq<<<dim3(MROWS / 64), dim3(256), 0, stream>>>(x, entry_w, entry_b, wtrig, xbf);
    k_gemm_ln<<<dim3(MROWS / 64), dim3(512), 0, stream>>>(xbf, Wbf, skip_b, exit_b, gamma, beta, out);
}

// Round 4
// 207.845 us; speedup vs baseline: 1.4815x; 1.1341x over previous
//
#include <hip/hip_runtime.h>
#include <hip/hip_bf16.h>

typedef unsigned short u16;
typedef unsigned int u32;
typedef __attribute__((ext_vector_type(8))) short bf16x8;
typedef __attribute__((ext_vector_type(4))) float f32x4;
typedef __attribute__((ext_vector_type(16))) float f32x16;   // SSA statevector slice

__device__ __forceinline__ u16 f2bf(float f) {
    u32 u = __float_as_uint(f);
    u32 r = (u + 0x7fffu + ((u >> 16) & 1u)) >> 16;   // RNE
    return (u16)r;
}
__device__ __forceinline__ float sx(float v, int m) { return __shfl_xor(v, m, 64); }

#define MROWS 32768
#define IN_D  512
#define OUT_D 512
#define KP    544
#define NQ    6

#define WS_XBF   0                       // u16 [32768][544]
#define WS_WBF   35651584                // u16 [512][544]
#define WS_WTRIG (35651584 + 557056)     // float[96]: 12 merged 2x2 complex mats

// ---------------------------------------------------------------------------
// kernel 0: pack W' = [skip_w | exit_w | 0] bf16; merged layer gates U=RZ*RY*RX
// ---------------------------------------------------------------------------
__global__ void k_setup(const float* __restrict__ skip_w,
                        const float* __restrict__ exit_w,
                        const float* __restrict__ vqc_w,
                        u16* __restrict__ Wbf,
                        float* __restrict__ wtrig) {
    int n = blockIdx.x;           // 512 blocks
    int t = threadIdx.x;          // 64 threads
    for (int c = t; c < KP; c += 64) {
        float v;
        if (c < 512)      v = skip_w[n * 512 + c];
        else if (c < 518) v = exit_w[n * 6 + (c - 512)];
        else              v = 0.0f;
        Wbf[n * KP + c] = f2bf(v);
    }
    if (blockIdx.x == 0 && t < 12) {
        int l = t / 6, i = t % 6;
        float c0 = cosf(0.5f * vqc_w[l * 18 + i]),      s0 = sinf(0.5f * vqc_w[l * 18 + i]);
        float c1 = cosf(0.5f * vqc_w[l * 18 + 6 + i]),  s1 = sinf(0.5f * vqc_w[l * 18 + 6 + i]);
        float c2 = cosf(0.5f * vqc_w[l * 18 + 12 + i]), s2 = sinf(0.5f * vqc_w[l * 18 + 12 + i]);
        float M00r = c1 * c0, M00i =  s1 * s0;
        float M01r = -s1 * c0, M01i = -c1 * s0;
        float M10r =  s1 * c0, M10i = -c1 * s0;
        float M11r = c1 * c0, M11i = -s1 * s0;
        float* o = wtrig + t * 8;
        o[0] = M00r * c2 + M00i * s2;  o[1] = M00i * c2 - M00r * s2;
        o[2] = M01r * c2 + M01i * s2;  o[3] = M01i * c2 - M01r * s2;
        o[4] = M10r * c2 - M10i * s2;  o[5] = M10i * c2 + M10r * s2;
        o[6] = M11r * c2 - M11i * s2;  o[7] = M11i * c2 + M11r * s2;
    }
}

// ---------------------------------------------------------------------------
// gate helpers on vector-register state (4 lanes/row, 16 amps/lane)
// ---------------------------------------------------------------------------
template<int M>
__device__ __forceinline__ void v_real(f32x16& ar, f32x16& ai,
                                       float g00, float g01, float g10, float g11) {
#pragma unroll
    for (int k = 0; k < 16; ++k) if (!(k & M)) {
        const int k1 = k | M;
        float a0 = ar[k], a1 = ar[k1];
        ar[k]  = g00 * a0 + g01 * a1;
        ar[k1] = g10 * a0 + g11 * a1;
        float b0 = ai[k], b1 = ai[k1];
        ai[k]  = g00 * b0 + g01 * b1;
        ai[k1] = g10 * b0 + g11 * b1;
    }
}
template<int M>
__device__ __forceinline__ void v_rz(f32x16& ar, f32x16& ai, float c, float s) {
#pragma unroll
    for (int k = 0; k < 16; ++k) {
        float u = (k & M) ? -s : s;
        float nr = c * ar[k] + u * ai[k];
        ai[k] = c * ai[k] - u * ar[k];
        ar[k] = nr;
    }
}
template<int M>
__device__ __forceinline__ void v_cplx(f32x16& ar, f32x16& ai,
                                       float2 u00, float2 u01, float2 u10, float2 u11) {
#pragma unroll
    for (int k = 0; k < 16; ++k) if (!(k & M)) {
        const int k1 = k | M;
        float a0r = ar[k], a0i = ai[k], a1r = ar[k1], a1i = ai[k1];
        ar[k]  = u00.x * a0r - u00.y * a0i + u01.x * a1r - u01.y * a1i;
        ai[k]  = u00.x * a0i + u00.y * a0r + u01.x * a1i + u01.y * a1r;
        ar[k1] = u10.x * a0r - u10.y * a0i + u11.x * a1r - u11.y * a1i;
        ai[k1] = u10.x * a0i + u10.y * a0r + u11.x * a1i + u11.y * a1r;
    }
}
template<int CM, int TM>
__device__ __forceinline__ void v_cnot(f32x16& ar, f32x16& ai) {
#pragma unroll
    for (int k = 0; k < 16; ++k) if ((k & CM) && !(k & TM)) {
        const int k1 = k | TM;
        float t = ar[k]; ar[k] = ar[k1]; ar[k1] = t;
        t = ai[k]; ai[k] = ai[k1]; ai[k1] = t;
    }
}
__device__ __forceinline__ void vx_real(f32x16& ar, f32x16& ai, int xm, bool b,
                                        float g00, float g01, float g10, float g11) {
    float gs = b ? g11 : g00, go = b ? g10 : g01;
#pragma unroll
    for (int k = 0; k < 16; ++k) {
        float pr = sx(ar[k], xm), pi = sx(ai[k], xm);
        ar[k] = gs * ar[k] + go * pr;
        ai[k] = gs * ai[k] + go * pi;
    }
}
__device__ __forceinline__ void vx_rz(f32x16& ar, f32x16& ai, bool b, float c, float s) {
    float u = b ? -s : s;
#pragma unroll
    for (int k = 0; k < 16; ++k) {
        float nr = c * ar[k] + u * ai[k];
        ai[k] = c * ai[k] - u * ar[k];
        ar[k] = nr;
    }
}
__device__ __forceinline__ void vx_cplx(f32x16& ar, f32x16& ai, int xm, bool b,
                                        float2 u00, float2 u01, float2 u10, float2 u11) {
    float2 us, uo;
    us.x = b ? u11.x : u00.x; us.y = b ? u11.y : u00.y;
    uo.x = b ? u10.x : u01.x; uo.y = b ? u10.y : u01.y;
#pragma unroll
    for (int k = 0; k < 16; ++k) {
        float pr = sx(ar[k], xm), pi = sx(ai[k], xm);
        float nr = us.x * ar[k] - us.y * ai[k] + uo.x * pr - uo.y * pi;
        ai[k] = us.x * ai[k] + us.y * ar[k] + uo.x * pi + uo.y * pr;
        ar[k] = nr;
    }
}

// ---------------------------------------------------------------------------
// kernel 1: entry GEMV + statevector sim, 4 lanes per row; state in SSA vectors
// ---------------------------------------------------------------------------
__global__ __launch_bounds__(256) void k_zq(const float* __restrict__ x,
                                            const float* __restrict__ entry_w,
                                            const float* __restrict__ entry_b,
                                            const float* __restrict__ wtrig,
                                            u16* __restrict__ xbf) {
    const int lane = threadIdx.x & 63;
    const int wid  = threadIdx.x >> 6;
    const int grp  = lane >> 2;
    const int sub  = lane & 3;
    const int row  = blockIdx.x * 64 + wid * 16 + grp;
    const bool b4 = (sub & 1) != 0;
    const bool b5 = (sub & 2) != 0;

    // ---- phase 1: dot + bf16 pack (lane covers cols i*32+sub*8, 8 wide) ----
    float d[NQ] = {0, 0, 0, 0, 0, 0};
#pragma unroll 4
    for (int i = 0; i < 16; ++i) {
        const float4* xp = (const float4*)(x + (size_t)row * IN_D + i * 32 + sub * 8);
        float4 xa = xp[0], xb = xp[1];
        union { u16 u[8]; uint4 v; } pk;
        pk.u[0] = f2bf(xa.x); pk.u[1] = f2bf(xa.y); pk.u[2] = f2bf(xa.z); pk.u[3] = f2bf(xa.w);
        pk.u[4] = f2bf(xb.x); pk.u[5] = f2bf(xb.y); pk.u[6] = f2bf(xb.z); pk.u[7] = f2bf(xb.w);
        *(uint4*)(xbf + (size_t)row * KP + i * 32 + sub * 8) = pk.v;
#pragma unroll
        for (int j = 0; j < NQ; ++j) {
            const float4* wp = (const float4*)(entry_w + j * IN_D + i * 32 + sub * 8);
            float4 wa = wp[0], wb = wp[1];
            d[j] += xa.x * wa.x + xa.y * wa.y + xa.z * wa.z + xa.w * wa.w
                  + xb.x * wb.x + xb.y * wb.y + xb.z * wb.z + xb.w * wb.w;
        }
    }
    float z[NQ];
#pragma unroll
    for (int j = 0; j < NQ; ++j) {
        d[j] += sx(d[j], 1);
        d[j] += sx(d[j], 2);
        z[j] = d[j] + entry_b[j];
    }

    float cy[NQ], sy[NQ], cz[NQ], szv[NQ];
#pragma unroll
    for (int j = 0; j < NQ; ++j) {
        float zj = z[j];
        float c1 = rsqrtf(1.0f + zj * zj);
        cy[j] = sqrtf(0.5f * (1.0f + c1));
        sy[j] = copysignf(sqrtf(fmaxf(0.5f * (1.0f - c1), 0.0f)), zj);
        float w  = zj * zj;
        float c2 = rsqrtf(1.0f + w * w);
        cz[j] = sqrtf(0.5f * (1.0f + c2));
        szv[j] = sqrtf(fmaxf(0.5f * (1.0f - c2), 0.0f));
    }

    // ---- phase 2: statevector in two SSA vectors (never an alloca) ----
    f32x16 ar = 0.0f, ai = 0.0f;
    if (sub == 0) ar[0] = 1.0f;

    const float Kc = 0.70710678118f;
#define ENCR(i) { float g00 = Kc*(cy[i]-sy[i]), g01 = Kc*(cy[i]+sy[i]); \
                  float g10 = Kc*(sy[i]+cy[i]), g11 = Kc*(sy[i]-cy[i]); \
                  v_real<(1 << i)>(ar, ai, g00, g01, g10, g11); \
                  v_rz<(1 << i)>(ar, ai, cz[i], szv[i]); }
    ENCR(0) ENCR(1) ENCR(2) ENCR(3)
#undef ENCR
    { float g00 = Kc*(cy[4]-sy[4]), g01 = Kc*(cy[4]+sy[4]);
      float g10 = Kc*(sy[4]+cy[4]), g11 = Kc*(sy[4]-cy[4]);
      vx_real(ar, ai, 1, b4, g00, g01, g10, g11);
      vx_rz(ar, ai, b4, cz[4], szv[4]); }
    { float g00 = Kc*(cy[5]-sy[5]), g01 = Kc*(cy[5]+sy[5]);
      float g10 = Kc*(sy[5]+cy[5]), g11 = Kc*(sy[5]-cy[5]);
      vx_real(ar, ai, 2, b5, g00, g01, g10, g11);
      vx_rz(ar, ai, b5, cz[5], szv[5]); }

    const float2* wu = (const float2*)wtrig;
#pragma unroll
    for (int l = 0; l < 2; ++l) {
        v_cnot<1, 2>(ar, ai); v_cnot<2, 4>(ar, ai); v_cnot<4, 8>(ar, ai);
        // (3,4): ctrl bit3 in-reg, tgt bit4 cross (xor 1)
#pragma unroll
        for (int k = 0; k < 16; ++k) if (k & 8) {
            ar[k] = sx(ar[k], 1); ai[k] = sx(ai[k], 1);
        }
        // (4,5): ctrl bit4 = sub&1, tgt bit5 cross (xor 2)
#pragma unroll
        for (int k = 0; k < 16; ++k) {
            float pr = sx(ar[k], 2); ar[k] = b4 ? pr : ar[k];
            float pi = sx(ai[k], 2); ai[k] = b4 ? pi : ai[k];
        }
        // (5,0): ctrl bit5 = sub&2, tgt bit0 in-reg
#pragma unroll
        for (int k = 0; k < 16; k += 2) {
            float t0r = ar[k], t0i = ai[k];
            ar[k]     = b5 ? ar[k + 1] : ar[k];
            ai[k]     = b5 ? ai[k + 1] : ai[k];
            ar[k + 1] = b5 ? t0r : ar[k + 1];
            ai[k + 1] = b5 ? t0i : ai[k + 1];
        }
#define ROTR(i) { int bx = (l * 6 + i) * 4; \
                  v_cplx<(1 << i)>(ar, ai, wu[bx], wu[bx+1], wu[bx+2], wu[bx+3]); }
        ROTR(0) ROTR(1) ROTR(2) ROTR(3)
#undef ROTR
        { int bx = (l * 6 + 4) * 4; vx_cplx(ar, ai, 1, b4, wu[bx], wu[bx+1], wu[bx+2], wu[bx+3]); }
        { int bx = (l * 6 + 5) * 4; vx_cplx(ar, ai, 2, b5, wu[bx], wu[bx+1], wu[bx+2], wu[bx+3]); }
        if (l == 0) {
#define REUPR(i) { v_real<(1 << i)>(ar, ai, cy[i], -sy[i], sy[i], cy[i]); \
                   v_rz<(1 << i)>(ar, ai, cz[i], szv[i]); }
            REUPR(0) REUPR(1) REUPR(2) REUPR(3)
#undef REUPR
            vx_real(ar, ai, 1, b4, cy[4], -sy[4], sy[4], cy[4]);
            vx_rz(ar, ai, b4, cz[4], szv[4]);
            vx_real(ar, ai, 2, b5, cy[5], -sy[5], sy[5], cy[5]);
            vx_rz(ar, ai, b5, cz[5], szv[5]);
        }
    }

    // ---- measure <Z_i> ----
    float e[NQ] = {0, 0, 0, 0, 0, 0};
    float tl = 0.0f;
#pragma unroll
    for (int k = 0; k < 16; ++k) {
        float p = ar[k] * ar[k] + ai[k] * ai[k];
        tl += p;
        e[0] += (k & 1) ? -p : p;
        e[1] += (k & 2) ? -p : p;
        e[2] += (k & 4) ? -p : p;
        e[3] += (k & 8) ? -p : p;
    }
    e[4] = b4 ? -tl : tl;
    e[5] = b5 ? -tl : tl;
#pragma unroll
    for (int j = 0; j < NQ; ++j) {
        e[j] += sx(e[j], 1);
        e[j] += sx(e[j], 2);
    }

    union { u16 u[8]; uint4 v; } t0;
#pragma unroll
    for (int j = 0; j < NQ; ++j) t0.u[j] = f2bf(z[j] + e[j]);
    t0.u[6] = 0; t0.u[7] = 0;
    uint4 tv; tv.x = tv.y = tv.z = tv.w = 0;
    if (sub == 0) tv = t0.v;
    *(uint4*)(xbf + (size_t)row * KP + 512 + sub * 8) = tv;
}

// ---------------------------------------------------------------------------
// kernel 2: A-tile (64x544) staged in LDS ONCE (padded stride, conflict-free
// b128 reads), B streamed direct from L2 with register double-buffer.
// NO barriers in the K-loop. Fused bias + full-row LN + fp32 store.
// ---------------------------------------------------------------------------
#define SA_STRIDE 552   // u16 units = 276 words; c16*276%32 spreads banks evenly

__global__ __launch_bounds__(512) void k_gemm_ln(const u16* __restrict__ xbf,
                                                 const u16* __restrict__ Wbf,
                                                 const float* __restrict__ skip_b,
                                                 const float* __restrict__ exit_b,
                                                 const float* __restrict__ gamma,
                                                 const float* __restrict__ beta,
                                                 float* __restrict__ out) {
    __shared__ __align__(16) u16 sA[64 * SA_STRIDE];   // 70656 B
    __shared__ float ps[8][64][2];
    __shared__ float stats[64][2];

    const int tid  = threadIdx.x;
    const int wid  = tid >> 6;
    const int lane = tid & 63;
    const int q    = lane >> 4;
    const int c16  = lane & 15;
    const int m0   = blockIdx.x * 64;

    // ---- stage A-tile once: 64 rows x 68 16B-chunks ----
    {
        int row = tid >> 3, c0 = tid & 7;
        const u16* src = xbf + (size_t)(m0 + row) * KP;
        u16* dst = sA + row * SA_STRIDE;
#pragma unroll
        for (int j = 0; j < 9; ++j) {
            int col = c0 + j * 8;
            if (col < 68) *(uint4*)(dst + col * 8) = *(const uint4*)(src + col * 8);
        }
    }
    __syncthreads();

    f32x4 acc[4][4];
#pragma unroll
    for (int mt = 0; mt < 4; ++mt)
#pragma unroll
        for (int nt = 0; nt < 4; ++nt)
#pragma unroll
            for (int r = 0; r < 4; ++r) acc[mt][nt][r] = 0.0f;

    const u16* bB = Wbf + (size_t)(wid * 64 + c16) * KP + q * 8;
    const u16* aL = sA + c16 * SA_STRIDE + q * 8;

    // register double-buffer for B; zero barriers in the loop
    bf16x8 bcur[4], bnxt[4];
#pragma unroll
    for (int nt = 0; nt < 4; ++nt)
        bcur[nt] = *(const bf16x8*)(bB + (size_t)nt * 16 * KP);

#pragma unroll 1
    for (int ks = 0; ks < 17; ++ks) {
        if (ks < 16) {
#pragma unroll
            for (int nt = 0; nt < 4; ++nt)
                bnxt[nt] = *(const bf16x8*)(bB + (size_t)nt * 16 * KP + (ks + 1) * 32);
        }
        bf16x8 af[4];
#pragma unroll
        for (int mt = 0; mt < 4; ++mt)
            af[mt] = *(const bf16x8*)(aL + mt * 16 * SA_STRIDE + ks * 32);
#pragma unroll
        for (int mt = 0; mt < 4; ++mt)
#pragma unroll
            for (int nt = 0; nt < 4; ++nt)
                acc[mt][nt] = __builtin_amdgcn_mfma_f32_16x16x32_bf16(af[mt], bcur[nt], acc[mt][nt], 0, 0, 0);
#pragma unroll
        for (int nt = 0; nt < 4; ++nt) bcur[nt] = bnxt[nt];
    }

    // ---- epilogue: bias, LN over full 512-col row, store fp32 ----
    float bias[4], gg[4], bb[4];
#pragma unroll
    for (int nt = 0; nt < 4; ++nt) {
        int n = wid * 64 + nt * 16 + c16;
        bias[nt] = skip_b[n] + exit_b[n];
        gg[nt] = gamma[n];
        bb[nt] = beta[n];
    }
#pragma unroll
    for (int mt = 0; mt < 4; ++mt)
#pragma unroll
        for (int nt = 0; nt < 4; ++nt)
#pragma unroll
            for (int r = 0; r < 4; ++r) acc[mt][nt][r] += bias[nt];

#pragma unroll
    for (int mt = 0; mt < 4; ++mt)
#pragma unroll
        for (int r = 0; r < 4; ++r) {
            float s1 = 0.0f, s2 = 0.0f;
#pragma unroll
            for (int nt = 0; nt < 4; ++nt) {
                float v = acc[mt][nt][r];
                s1 += v; s2 += v * v;
            }
#pragma unroll
            for (int off = 1; off < 16; off <<= 1) {
                s1 += sx(s1, off);
                s2 += sx(s2, off);
            }
            if (c16 == r) {
                int m = mt * 16 + q * 4 + r;
                ps[wid][m][0] = s1;
                ps[wid][m][1] = s2;
            }
        }
    __syncthreads();
    if (tid < 64) {
        float s1 = 0.0f, s2 = 0.0f;
#pragma unroll
        for (int w2 = 0; w2 < 8; ++w2) { s1 += ps[w2][tid][0]; s2 += ps[w2][tid][1]; }
        float mu  = s1 * (1.0f / 512.0f);
        float var = s2 * (1.0f / 512.0f) - mu * mu;
        stats[tid][0] = mu;
        stats[tid][1] = rsqrtf(var + 1e-5f);
    }
    __syncthreads();

#pragma unroll
    for (int mt = 0; mt < 4; ++mt)
#pragma unroll
        for (int r = 0; r < 4; ++r) {
            int m = mt * 16 + q * 4 + r;
            float mu = stats[m][0], rs = stats[m][1];
#pragma unroll
            for (int nt = 0; nt < 4; ++nt) {
                float v = (acc[mt][nt][r] - mu) * rs * gg[nt] + bb[nt];
                out[(size_t)(m0 + m) * OUT_D + wid * 64 + nt * 16 + c16] = v;
            }
        }
}

// ---------------------------------------------------------------------------
extern "C" void kernel_launch(void* const* d_in, const int* in_sizes, int n_in,
                              void* d_out, int out_size, void* d_ws, size_t ws_size,
                              hipStream_t stream) {
    const float* x       = (const float*)d_in[0];
    const float* entry_w = (const float*)d_in[1];
    const float* entry_b = (const float*)d_in[2];
    const float* exit_w  = (const float*)d_in[3];
    const float* exit_b  = (const float*)d_in[4];
    const float* skip_w  = (const float*)d_in[5];
    const float* skip_b  = (const float*)d_in[6];
    const float* vqc_w   = (const float*)d_in[7];
    const float* gamma   = (const float*)d_in[8];
    const float* beta    = (const float*)d_in[9];
    float* out = (float*)d_out;

    char* ws = (char*)d_ws;
    u16*   xbf   = (u16*)(ws + WS_XBF);
    u16*   Wbf   = (u16*)(ws + WS_WBF);
    float* wtrig = (float*)(ws + WS_WTRIG);

    k_setup<<<dim3(512), dim3(64), 0, stream>>>(skip_w, exit_w, vqc_w, Wbf, wtrig);
    k_zq<<<dim3(MROWS / 64), dim3(256), 0, stream>>>(x, entry_w, entry_b, wtrig, xbf);
    k_gemm_ln<<<dim3(MROWS / 64), dim3(512), 0, stream>>>(xbf, Wbf, skip_b, exit_b, gamma, beta, out);
}

// Round 5
// 186.595 us; speedup vs baseline: 1.6502x; 1.1139x over previous
//
#include <hip/hip_runtime.h>
#include <hip/hip_bf16.h>

typedef unsigned short u16;
typedef unsigned int u32;
typedef __attribute__((ext_vector_type(8))) short bf16x8;
typedef __attribute__((ext_vector_type(4))) float f32x4;
typedef __attribute__((ext_vector_type(8))) float f32x8;   // SSA statevector slice

__device__ __forceinline__ u16 f2bf(float f) {
    u32 u = __float_as_uint(f);
    u32 r = (u + 0x7fffu + ((u >> 16) & 1u)) >> 16;   // RNE
    return (u16)r;
}
__device__ __forceinline__ float sx(float v, int m) { return __shfl_xor(v, m, 64); }

#define MROWS 32768
#define IN_D  512
#define OUT_D 512
#define KP    544
#define NQ    6
#define SA_STRIDE 552   // u16; 276 words -> uniform bank spread for b128 frags

#define WS_WOP   0              // u16, MFMA-operand-ordered W': 32*17*64*8 = 557056 B
#define WS_WTRIG 557056         // float[96]

// ---------------------------------------------------------------------------
// kernel 0: W' = [skip_w | exit_w | 0] -> bf16 in MFMA B-operand order:
// chunk index ((nblk*17 + ks)*64 + lane), lane&15 = n-offset, lane>>4 = k-chunk
// ---------------------------------------------------------------------------
__global__ void k_setup(const float* __restrict__ skip_w,
                        const float* __restrict__ exit_w,
                        const float* __restrict__ vqc_w,
                        u16* __restrict__ Wop,
                        float* __restrict__ wtrig) {
    const int nblk = blockIdx.x;          // 32 blocks
    const int t = threadIdx.x;            // 64 threads
    const int n = nblk * 16 + (t & 15);
    const int q = t >> 4;
    for (int ks = 0; ks < 17; ++ks) {
        union { u16 u[8]; uint4 v; } pk;
#pragma unroll
        for (int j = 0; j < 8; ++j) {
            int k = ks * 32 + q * 8 + j;
            float v;
            if (k < 512)      v = skip_w[n * 512 + k];
            else if (k < 518) v = exit_w[n * 6 + (k - 512)];
            else              v = 0.0f;
            pk.u[j] = f2bf(v);
        }
        *(uint4*)(Wop + ((size_t)(nblk * 17 + ks) * 64 + t) * 8) = pk.v;
    }
    if (nblk == 0 && t < 12) {
        int l = t / 6, i = t % 6;
        float c0 = cosf(0.5f * vqc_w[l * 18 + i]),      s0 = sinf(0.5f * vqc_w[l * 18 + i]);
        float c1 = cosf(0.5f * vqc_w[l * 18 + 6 + i]),  s1 = sinf(0.5f * vqc_w[l * 18 + 6 + i]);
        float c2 = cosf(0.5f * vqc_w[l * 18 + 12 + i]), s2 = sinf(0.5f * vqc_w[l * 18 + 12 + i]);
        float M00r = c1 * c0, M00i =  s1 * s0;
        float M01r = -s1 * c0, M01i = -c1 * s0;
        float M10r =  s1 * c0, M10i = -c1 * s0;
        float M11r = c1 * c0, M11i = -s1 * s0;
        float* o = wtrig + t * 8;
        o[0] = M00r * c2 + M00i * s2;  o[1] = M00i * c2 - M00r * s2;
        o[2] = M01r * c2 + M01i * s2;  o[3] = M01i * c2 - M01r * s2;
        o[4] = M10r * c2 - M10i * s2;  o[5] = M10i * c2 + M10r * s2;
        o[6] = M11r * c2 - M11i * s2;  o[7] = M11i * c2 + M11r * s2;
    }
}

// ---------------------------------------------------------------------------
// gate helpers: 8 lanes/row, 8 amps/lane; qubits 0-2 in-reg, 3-5 cross-lane
// ---------------------------------------------------------------------------
template<int M>
__device__ __forceinline__ void v8_real(f32x8& ar, f32x8& ai,
                                        float g00, float g01, float g10, float g11) {
#pragma unroll
    for (int k = 0; k < 8; ++k) if (!(k & M)) {
        const int k1 = k | M;
        float a0 = ar[k], a1 = ar[k1];
        ar[k]  = g00 * a0 + g01 * a1;
        ar[k1] = g10 * a0 + g11 * a1;
        float b0 = ai[k], b1 = ai[k1];
        ai[k]  = g00 * b0 + g01 * b1;
        ai[k1] = g10 * b0 + g11 * b1;
    }
}
template<int M>
__device__ __forceinline__ void v8_rz(f32x8& ar, f32x8& ai, float c, float s) {
#pragma unroll
    for (int k = 0; k < 8; ++k) {
        float u = (k & M) ? -s : s;
        float nr = c * ar[k] + u * ai[k];
        ai[k] = c * ai[k] - u * ar[k];
        ar[k] = nr;
    }
}
template<int M>
__device__ __forceinline__ void v8_cplx(f32x8& ar, f32x8& ai,
                                        float2 u00, float2 u01, float2 u10, float2 u11) {
#pragma unroll
    for (int k = 0; k < 8; ++k) if (!(k & M)) {
        const int k1 = k | M;
        float a0r = ar[k], a0i = ai[k], a1r = ar[k1], a1i = ai[k1];
        ar[k]  = u00.x * a0r - u00.y * a0i + u01.x * a1r - u01.y * a1i;
        ai[k]  = u00.x * a0i + u00.y * a0r + u01.x * a1i + u01.y * a1r;
        ar[k1] = u10.x * a0r - u10.y * a0i + u11.x * a1r - u11.y * a1i;
        ai[k1] = u10.x * a0i + u10.y * a0r + u11.x * a1i + u11.y * a1r;
    }
}
template<int CM, int TM>
__device__ __forceinline__ void v8_cnot(f32x8& ar, f32x8& ai) {
#pragma unroll
    for (int k = 0; k < 8; ++k) if ((k & CM) && !(k & TM)) {
        const int k1 = k | TM;
        float t = ar[k]; ar[k] = ar[k1]; ar[k1] = t;
        t = ai[k]; ai[k] = ai[k1]; ai[k1] = t;
    }
}
__device__ __forceinline__ void vx8_real(f32x8& ar, f32x8& ai, int xm, bool b,
                                         float g00, float g01, float g10, float g11) {
    float gs = b ? g11 : g00, go = b ? g10 : g01;
#pragma unroll
    for (int k = 0; k < 8; ++k) {
        float pr = sx(ar[k], xm), pi = sx(ai[k], xm);
        ar[k] = gs * ar[k] + go * pr;
        ai[k] = gs * ai[k] + go * pi;
    }
}
__device__ __forceinline__ void vx8_rz(f32x8& ar, f32x8& ai, bool b, float c, float s) {
    float u = b ? -s : s;
#pragma unroll
    for (int k = 0; k < 8; ++k) {
        float nr = c * ar[k] + u * ai[k];
        ai[k] = c * ai[k] - u * ar[k];
        ar[k] = nr;
    }
}
__device__ __forceinline__ void vx8_cplx(f32x8& ar, f32x8& ai, int xm, bool b,
                                         float2 u00, float2 u01, float2 u10, float2 u11) {
    float2 us, uo;
    us.x = b ? u11.x : u00.x; us.y = b ? u11.y : u00.y;
    uo.x = b ? u10.x : u01.x; uo.y = b ? u10.y : u01.y;
#pragma unroll
    for (int k = 0; k < 8; ++k) {
        float pr = sx(ar[k], xm), pi = sx(ai[k], xm);
        float nr = us.x * ar[k] - us.y * ai[k] + uo.x * pr - uo.y * pi;
        ai[k] = us.x * ai[k] + us.y * ar[k] + uo.x * pi + uo.y * pr;
        ar[k] = nr;
    }
}

// ---------------------------------------------------------------------------
// fused kernel: zq (8 lanes/row -> A-tile in LDS) + MFMA GEMM + LN
// ---------------------------------------------------------------------------
__global__ __launch_bounds__(512) void k_fused(const float* __restrict__ x,
                                               const float* __restrict__ entry_w,
                                               const float* __restrict__ entry_b,
                                               const float* __restrict__ wtrig,
                                               const u16* __restrict__ Wop,
                                               const float* __restrict__ skip_b,
                                               const float* __restrict__ exit_b,
                                               const float* __restrict__ gamma,
                                               const float* __restrict__ beta,
                                               float* __restrict__ out) {
    __shared__ __align__(16) u16 sA[64 * SA_STRIDE];   // 70656 B
    __shared__ float ps[8][64][2];
    __shared__ float stats[64][2];

    const int tid  = threadIdx.x;
    const int wid  = tid >> 6;
    const int lane = tid & 63;
    const int m0   = blockIdx.x * 64;

    // ================= phase 1: entry GEMV + bf16 pack to LDS =================
    const int grp = lane >> 3;            // row within wave's 8
    const int sub = lane & 7;
    const int lrow = wid * 8 + grp;       // 0..63
    const int row = m0 + lrow;
    const bool b3 = (sub & 1) != 0;
    const bool b4 = (sub & 2) != 0;
    const bool b5 = (sub & 4) != 0;

    float d[NQ] = {0, 0, 0, 0, 0, 0};
#pragma unroll
    for (int i = 0; i < 8; ++i) {
        const float4* xp = (const float4*)(x + (size_t)row * IN_D + i * 64 + sub * 8);
        float4 xa = xp[0], xb = xp[1];
        union { u16 u[8]; uint4 v; } pk;
        pk.u[0] = f2bf(xa.x); pk.u[1] = f2bf(xa.y); pk.u[2] = f2bf(xa.z); pk.u[3] = f2bf(xa.w);
        pk.u[4] = f2bf(xb.x); pk.u[5] = f2bf(xb.y); pk.u[6] = f2bf(xb.z); pk.u[7] = f2bf(xb.w);
        *(uint4*)(sA + lrow * SA_STRIDE + i * 64 + sub * 8) = pk.v;
#pragma unroll
        for (int j = 0; j < NQ; ++j) {
            const float4* wp = (const float4*)(entry_w + j * IN_D + i * 64 + sub * 8);
            float4 wa = wp[0], wb = wp[1];
            d[j] += xa.x * wa.x + xa.y * wa.y + xa.z * wa.z + xa.w * wa.w
                  + xb.x * wb.x + xb.y * wb.y + xb.z * wb.z + xb.w * wb.w;
        }
    }
    float z[NQ];
#pragma unroll
    for (int j = 0; j < NQ; ++j) {
        d[j] += sx(d[j], 1);
        d[j] += sx(d[j], 2);
        d[j] += sx(d[j], 4);
        z[j] = d[j] + entry_b[j];
    }

    float cy[NQ], sy[NQ], cz[NQ], szv[NQ];
#pragma unroll
    for (int j = 0; j < NQ; ++j) {
        float zj = z[j];
        float c1 = rsqrtf(1.0f + zj * zj);
        cy[j] = sqrtf(0.5f * (1.0f + c1));
        sy[j] = copysignf(sqrtf(fmaxf(0.5f * (1.0f - c1), 0.0f)), zj);
        float w  = zj * zj;
        float c2 = rsqrtf(1.0f + w * w);
        cz[j] = sqrtf(0.5f * (1.0f + c2));
        szv[j] = sqrtf(fmaxf(0.5f * (1.0f - c2), 0.0f));
    }

    // ================= phase 2: statevector sim =================
    f32x8 ar = 0.0f, ai = 0.0f;
    if (sub == 0) ar[0] = 1.0f;

    const float Kc = 0.70710678118f;
#define ENCR(i) { float g00 = Kc*(cy[i]-sy[i]), g01 = Kc*(cy[i]+sy[i]); \
                  float g10 = Kc*(sy[i]+cy[i]), g11 = Kc*(sy[i]-cy[i]); \
                  v8_real<(1 << i)>(ar, ai, g00, g01, g10, g11); \
                  v8_rz<(1 << i)>(ar, ai, cz[i], szv[i]); }
    ENCR(0) ENCR(1) ENCR(2)
#undef ENCR
#define ENCX(i, xm, bb_) { float g00 = Kc*(cy[i]-sy[i]), g01 = Kc*(cy[i]+sy[i]); \
                           float g10 = Kc*(sy[i]+cy[i]), g11 = Kc*(sy[i]-cy[i]); \
                           vx8_real(ar, ai, xm, bb_, g00, g01, g10, g11); \
                           vx8_rz(ar, ai, bb_, cz[i], szv[i]); }
    ENCX(3, 1, b3) ENCX(4, 2, b4) ENCX(5, 4, b5)
#undef ENCX

    const float2* wu = (const float2*)wtrig;
#pragma unroll
    for (int l = 0; l < 2; ++l) {
        // CNOT ring (0,1)(1,2) in-reg
        v8_cnot<1, 2>(ar, ai); v8_cnot<2, 4>(ar, ai);
        // (2,3): ctrl k-bit2, tgt sub-bit0 (xor 1): both partners swap
#pragma unroll
        for (int k = 0; k < 8; ++k) if (k & 4) {
            ar[k] = sx(ar[k], 1); ai[k] = sx(ai[k], 1);
        }
        // (3,4): ctrl sub-bit0, tgt sub-bit1 (xor 2)
#pragma unroll
        for (int k = 0; k < 8; ++k) {
            float pr = sx(ar[k], 2); ar[k] = b3 ? pr : ar[k];
            float pi = sx(ai[k], 2); ai[k] = b3 ? pi : ai[k];
        }
        // (4,5): ctrl sub-bit1, tgt sub-bit2 (xor 4)
#pragma unroll
        for (int k = 0; k < 8; ++k) {
            float pr = sx(ar[k], 4); ar[k] = b4 ? pr : ar[k];
            float pi = sx(ai[k], 4); ai[k] = b4 ? pi : ai[k];
        }
        // (5,0): ctrl sub-bit2, tgt k-bit0 in-reg
#pragma unroll
        for (int k = 0; k < 8; k += 2) {
            float t0r = ar[k], t0i = ai[k];
            ar[k]     = b5 ? ar[k + 1] : ar[k];
            ai[k]     = b5 ? ai[k + 1] : ai[k];
            ar[k + 1] = b5 ? t0r : ar[k + 1];
            ai[k + 1] = b5 ? t0i : ai[k + 1];
        }
        // merged parameterized rotations U = RZ*RY*RX
#define ROTR(i) { int bx = (l * 6 + i) * 4; \
                  v8_cplx<(1 << i)>(ar, ai, wu[bx], wu[bx+1], wu[bx+2], wu[bx+3]); }
        ROTR(0) ROTR(1) ROTR(2)
#undef ROTR
        { int bx = (l * 6 + 3) * 4; vx8_cplx(ar, ai, 1, b3, wu[bx], wu[bx+1], wu[bx+2], wu[bx+3]); }
        { int bx = (l * 6 + 4) * 4; vx8_cplx(ar, ai, 2, b4, wu[bx], wu[bx+1], wu[bx+2], wu[bx+3]); }
        { int bx = (l * 6 + 5) * 4; vx8_cplx(ar, ai, 4, b5, wu[bx], wu[bx+1], wu[bx+2], wu[bx+3]); }
        if (l == 0) {
#define REUPR(i) { v8_real<(1 << i)>(ar, ai, cy[i], -sy[i], sy[i], cy[i]); \
                   v8_rz<(1 << i)>(ar, ai, cz[i], szv[i]); }
            REUPR(0) REUPR(1) REUPR(2)
#undef REUPR
            vx8_real(ar, ai, 1, b3, cy[3], -sy[3], sy[3], cy[3]);
            vx8_rz(ar, ai, b3, cz[3], szv[3]);
            vx8_real(ar, ai, 2, b4, cy[4], -sy[4], sy[4], cy[4]);
            vx8_rz(ar, ai, b4, cz[4], szv[4]);
            vx8_real(ar, ai, 4, b5, cy[5], -sy[5], sy[5], cy[5]);
            vx8_rz(ar, ai, b5, cz[5], szv[5]);
        }
    }

    // measure <Z_i>
    float e[NQ];
    float tl = 0.0f, e0 = 0.0f, e1 = 0.0f, e2 = 0.0f;
#pragma unroll
    for (int k = 0; k < 8; ++k) {
        float p = ar[k] * ar[k] + ai[k] * ai[k];
        tl += p;
        e0 += (k & 1) ? -p : p;
        e1 += (k & 2) ? -p : p;
        e2 += (k & 4) ? -p : p;
    }
    e[0] = e0; e[1] = e1; e[2] = e2;
    e[3] = b3 ? -tl : tl;
    e[4] = b4 ? -tl : tl;
    e[5] = b5 ? -tl : tl;
#pragma unroll
    for (int j = 0; j < NQ; ++j) {
        e[j] += sx(e[j], 1);
        e[j] += sx(e[j], 2);
        e[j] += sx(e[j], 4);
    }

    // tail cols 512..543 in LDS (zq in 512..517, zeros beyond)
    if (sub < 4) {
        uint4 tv; tv.x = tv.y = tv.z = tv.w = 0;
        if (sub == 0) {
            union { u16 u[8]; uint4 v; } t0;
#pragma unroll
            for (int j = 0; j < NQ; ++j) t0.u[j] = f2bf(z[j] + e[j]);
            t0.u[6] = 0; t0.u[7] = 0;
            tv = t0.v;
        }
        *(uint4*)(sA + lrow * SA_STRIDE + 512 + sub * 8) = tv;
    }
    __syncthreads();

    // ================= phase 3: MFMA GEMM (no barriers in K-loop) =============
    const int q   = lane >> 4;
    const int c16 = lane & 15;

    f32x4 acc[4][4];
#pragma unroll
    for (int mt = 0; mt < 4; ++mt)
#pragma unroll
        for (int nt = 0; nt < 4; ++nt)
#pragma unroll
            for (int r = 0; r < 4; ++r) acc[mt][nt][r] = 0.0f;

    // B: coalesced operand-order loads; register double-buffer
    bf16x8 bcur[4], bnxt[4];
#pragma unroll
    for (int nt = 0; nt < 4; ++nt)
        bcur[nt] = *(const bf16x8*)(Wop + ((size_t)((wid * 4 + nt) * 17 + 0) * 64 + lane) * 8);

#pragma unroll 1
    for (int ks = 0; ks < 17; ++ks) {
        if (ks < 16) {
#pragma unroll
            for (int nt = 0; nt < 4; ++nt)
                bnxt[nt] = *(const bf16x8*)(Wop + ((size_t)((wid * 4 + nt) * 17 + ks + 1) * 64 + lane) * 8);
        }
        bf16x8 af[4];
#pragma unroll
        for (int mt = 0; mt < 4; ++mt)
            af[mt] = *(const bf16x8*)(sA + (mt * 16 + c16) * SA_STRIDE + ks * 32 + q * 8);
#pragma unroll
        for (int mt = 0; mt < 4; ++mt)
#pragma unroll
            for (int nt = 0; nt < 4; ++nt)
                acc[mt][nt] = __builtin_amdgcn_mfma_f32_16x16x32_bf16(af[mt], bcur[nt], acc[mt][nt], 0, 0, 0);
#pragma unroll
        for (int nt = 0; nt < 4; ++nt) bcur[nt] = bnxt[nt];
    }

    // ================= epilogue: bias + LN + store =================
    float bias[4], gg[4], bb[4];
#pragma unroll
    for (int nt = 0; nt < 4; ++nt) {
        int n = wid * 64 + nt * 16 + c16;
        bias[nt] = skip_b[n] + exit_b[n];
        gg[nt] = gamma[n];
        bb[nt] = beta[n];
    }
#pragma unroll
    for (int mt = 0; mt < 4; ++mt)
#pragma unroll
        for (int nt = 0; nt < 4; ++nt)
#pragma unroll
            for (int r = 0; r < 4; ++r) acc[mt][nt][r] += bias[nt];

#pragma unroll
    for (int mt = 0; mt < 4; ++mt)
#pragma unroll
        for (int r = 0; r < 4; ++r) {
            float s1 = 0.0f, s2 = 0.0f;
#pragma unroll
            for (int nt = 0; nt < 4; ++nt) {
                float v = acc[mt][nt][r];
                s1 += v; s2 += v * v;
            }
#pragma unroll
            for (int off = 1; off < 16; off <<= 1) {
                s1 += sx(s1, off);
                s2 += sx(s2, off);
            }
            if (c16 == r) {
                int m = mt * 16 + q * 4 + r;
                ps[wid][m][0] = s1;
                ps[wid][m][1] = s2;
            }
        }
    __syncthreads();
    if (tid < 64) {
        float s1 = 0.0f, s2 = 0.0f;
#pragma unroll
        for (int w2 = 0; w2 < 8; ++w2) { s1 += ps[w2][tid][0]; s2 += ps[w2][tid][1]; }
        float mu  = s1 * (1.0f / 512.0f);
        float var = s2 * (1.0f / 512.0f) - mu * mu;
        stats[tid][0] = mu;
        stats[tid][1] = rsqrtf(var + 1e-5f);
    }
    __syncthreads();

#pragma unroll
    for (int mt = 0; mt < 4; ++mt)
#pragma unroll
        for (int r = 0; r < 4; ++r) {
            int m = mt * 16 + q * 4 + r;
            float mu = stats[m][0], rs = stats[m][1];
#pragma unroll
            for (int nt = 0; nt < 4; ++nt) {
                float v = (acc[mt][nt][r] - mu) * rs * gg[nt] + bb[nt];
                out[(size_t)(m0 + m) * OUT_D + wid * 64 + nt * 16 + c16] = v;
            }
        }
}

// ---------------------------------------------------------------------------
extern "C" void kernel_launch(void* const* d_in, const int* in_sizes, int n_in,
                              void* d_out, int out_size, void* d_ws, size_t ws_size,
                              hipStream_t stream) {
    const float* x       = (const float*)d_in[0];
    const float* entry_w = (const float*)d_in[1];
    const float* entry_b = (const float*)d_in[2];
    const float* exit_w  = (const float*)d_in[3];
    const float* exit_b  = (const float*)d_in[4];
    const float* skip_w  = (const float*)d_in[5];
    const float* skip_b  = (const float*)d_in[6];
    const float* vqc_w   = (const float*)d_in[7];
    const float* gamma   = (const float*)d_in[8];
    const float* beta    = (const float*)d_in[9];
    float* out = (float*)d_out;

    char* ws = (char*)d_ws;
    u16*   Wop   = (u16*)(ws + WS_WOP);
    float* wtrig = (float*)(ws + WS_WTRIG);

    k_setup<<<dim3(32), dim3(64), 0, stream>>>(skip_w, exit_w, vqc_w, Wop, wtrig);
    k_fused<<<dim3(MROWS / 64), dim3(512), 0, stream>>>(x, entry_w, entry_b, wtrig, Wop,
                                                        skip_b, exit_b, gamma, beta, out);
}